// Round 28
// baseline (807.671 us; speedup 1.0000x reference)
//
#include <hip/hip_runtime.h>

#define BB 32
#define TT 16384

typedef __attribute__((ext_vector_type(8))) short bf16x8;
typedef __attribute__((ext_vector_type(4))) float f32x4;
typedef __attribute__((ext_vector_type(4))) int i32x4;

#define MFMA(A, B, C) __builtin_amdgcn_mfma_f32_16x16x32_bf16((A), (B), (C), 0, 0, 0)

__device__ __forceinline__ unsigned short bf16_rne(float f) {
    unsigned int u = __float_as_uint(f);
    return (unsigned short)((u + 0x7FFF + ((u >> 16) & 1)) >> 16);
}
__device__ __forceinline__ float bf16_to_f(unsigned short h) {
    return __uint_as_float(((unsigned int)h) << 16);
}
// 4 f32 -> 4 bf16 (RNE) in 2 instructions; memory order short[0..3] = v[0..3]
__device__ __forceinline__ uint2 pk4(f32x4 v) {
    uint2 r;
    asm("v_cvt_pk_bf16_f32 %0, %1, %2" : "=v"(r.x) : "v"(v[0]), "v"(v[1]));
    asm("v_cvt_pk_bf16_f32 %0, %1, %2" : "=v"(r.y) : "v"(v[2]), "v"(v[3]));
    return r;
}

__device__ __forceinline__ float fast_sigmoid(float x) {
    float e = __expf(-x);
    return __builtin_amdgcn_rcpf(1.0f + e);
}
__device__ __forceinline__ float fast_tanh(float x) {
    float ax = fabsf(x);
    float e = __expf(2.0f * ax);
    float r = 1.0f - 2.0f * __builtin_amdgcn_rcpf(1.0f + e);
    return copysignf(r, x);
}

// ---------------------------------------------------------------------------
// Weight prep (verified round 6): 7 fragments + 6 bias sets per layer.
//   lane l: row = l&15 (out-ch), q = l>>4, elem j=0..7.
// f0/f1: conv1 W1 hi/lo (replicated over q>>1):  src[j] = W1[row][8*(q&1)+j]
// f2..f5: gate Wf h0, Wf h1, Wg h0, Wg h1: src[j]=W[16h+row][8*(q&1)+j][q>>1]
// f6: out W2: src[j] = W2[row][8q+j]
// ---------------------------------------------------------------------------
__global__ void prep_kernel(const float* __restrict__ w1_first,
                            const float* __restrict__ b1_first,
                            const float* __restrict__ w1_post,
                            const float* __restrict__ b1_post,
                            const float* __restrict__ wf, const float* __restrict__ bfb,
                            const float* __restrict__ wg, const float* __restrict__ bgb,
                            const float* __restrict__ w2, const float* __restrict__ b2,
                            short* __restrict__ Wfrag, float* __restrict__ Bset) {
    int L = blockIdx.x;
    int l = threadIdx.x;
    int op = l & 15;
    int q = l >> 4;
    int i0 = (q & 1) << 3;
    int tap = q >> 1;

    float gbuf[6][8];
#pragma unroll
    for (int j = 0; j < 8; ++j) {
        gbuf[0][j] = (L == 0) ? 0.f
                   : w1_post[((size_t)(L - 1) * 16 + op) * 16 + i0 + j];
        gbuf[1][j] = wf[(((size_t)L * 32 + op) * 16 + i0 + j) * 2 + tap];
        gbuf[2][j] = wf[(((size_t)L * 32 + 16 + op) * 16 + i0 + j) * 2 + tap];
        gbuf[3][j] = wg[(((size_t)L * 32 + op) * 16 + i0 + j) * 2 + tap];
        gbuf[4][j] = wg[(((size_t)L * 32 + 16 + op) * 16 + i0 + j) * 2 + tap];
        gbuf[5][j] = w2[((size_t)L * 16 + op) * 32 + (q << 3) + j];
    }

    constexpr int gsel[7] = {0, 0, 1, 2, 3, 4, 5};
    constexpr int hsel[7] = {1, 0, 1, 1, 1, 1, 1};
#pragma unroll
    for (int f = 0; f < 7; ++f) {
        size_t base = (((size_t)L * 7 + f) * 64 + l) * 8;
#pragma unroll
        for (int j = 0; j < 8; ++j) {
            float v = gbuf[gsel[f]][j];
            unsigned short h = bf16_rne(v);
            Wfrag[base + j] = hsel[f] ? (short)h
                                      : (short)bf16_rne(v - bf16_to_f(h));
        }
    }

#pragma unroll
    for (int r = 0; r < 4; ++r) {
        int c = (q << 2) + r;
        float bv[6];
        bv[0] = (L == 0) ? b1_first[c] : b1_post[(size_t)(L - 1) * 16 + c];
        bv[1] = bfb[(size_t)L * 32 + c];
        bv[2] = bfb[(size_t)L * 32 + 16 + c];
        bv[3] = bgb[(size_t)L * 32 + c];
        bv[4] = bgb[(size_t)L * 32 + 16 + c];
        bv[5] = b2[(size_t)L * 16 + c];
#pragma unroll
        for (int s = 0; s < 6; ++s)
            Bset[(((size_t)L * 6 + s) * 64 + l) * 4 + r] = bv[s];
    }
}

// conv1 at one column. Global x stream is SINGLE bf16, 32B/pos:
// bytes 0-15 = ch0-7, 16-31 = ch8-15. One MFMA with A12 (= W_hi for q<2,
// W_lo for q>=2): W_hi*x + W_lo*x = W*x.  first: raw fp32 (B,1,T) input.
__device__ __forceinline__ f32x4 conv1_eval(bool first, const void* __restrict__ xin,
                                            const float* __restrict__ w1f,
                                            int b, int tp, int q,
                                            f32x4 b1v, bf16x8 A12) {
    const f32x4 zero = {0.f, 0.f, 0.f, 0.f};
    bool valid = ((unsigned)tp) < (unsigned)TT;
    f32x4 acc = valid ? b1v : zero;
    if (first) {
        const float* xf = (const float*)xin;
        float xv = valid ? xf[(size_t)b * TT + tp] : 0.f;
        const float4* w4 = (const float4*)w1f;
        float4 w = w4[q];
        acc[0] = fmaf(w.x, xv, acc[0]);
        acc[1] = fmaf(w.y, xv, acc[1]);
        acc[2] = fmaf(w.z, xv, acc[2]);
        acc[3] = fmaf(w.w, xv, acc[3]);
    } else {
        int tpc = valid ? tp : 0;
        const bf16x8 z8 = {0, 0, 0, 0, 0, 0, 0, 0};
        const bf16x8* xp = (const bf16x8*)((const char*)xin +
                            ((size_t)b * TT + tpc) * 32 + ((q & 1) << 4));
        bf16x8 bb = valid ? *xp : z8;
        acc = MFMA(A12, bb, acc);
    }
#pragma unroll
    for (int r = 0; r < 4; ++r) acc[r] = fmaxf(acc[r], 0.f);
    return acc;
}

// ===========================================================================
// SINGLE-LAYER kernel (r26/r27-verified: single-bf16 global x stream, ~18us,
// at its ~100MB memory roofline).  MODE: 0 = middle, 1 = first, 2 = last
// ===========================================================================
template <int MODE>
__global__ __launch_bounds__(256) void wn_layer(
    const void* __restrict__ xin, void* __restrict__ xout,
    float* __restrict__ skip, float* __restrict__ dout,
    const short* __restrict__ WfragL, const float* __restrict__ BsetL,
    const float* __restrict__ w1f, int d) {
    __shared__ char sm[8192];

    const int tid = threadIdx.x;
    const int wave = tid >> 6, lane = tid & 63;
    const int p = lane & 15, q = lane >> 4;

    const int blk = ((blockIdx.x & 7) << 10) + (blockIdx.x >> 3);
    const int b = blk >> 8;
    const int tbase = ((blk & 255) << 6) + (wave << 4);
    const int pl = d >> 1, pr = d - pl;

    char* xrb = sm + wave * 1024;
    char* zb = sm + 4096 + wave * 1024;
    const int xorb = (p & 8) << 2;

    const bf16x8* WF = (const bf16x8*)WfragL;
    const f32x4* BS = (const f32x4*)BsetL;

    const f32x4 b1v = BS[lane];
    bf16x8 A12 = {0, 0, 0, 0, 0, 0, 0, 0};
    if (MODE != 1) A12 = (q < 2) ? WF[lane] : WF[64 + lane];

#pragma unroll
    for (int g = 0; g < 2; ++g) {
        int ts = tbase + (g ? pr : -pl);
        f32x4 xr = conv1_eval(MODE == 1, xin, w1f, b, ts + p, q, b1v, A12);
        *(uint2*)(xrb + (g << 9) +
                  ((((q >> 1) << 8) + (p << 4) + ((q & 1) << 3)) ^ xorb)) = pk4(xr);
    }

    f32x4 xrC = {0.f, 0.f, 0.f, 0.f};
    if (MODE != 2)
        xrC = conv1_eval(MODE == 1, xin, w1f, b, tbase + p, q, b1v, A12);

    bf16x8 bxr = *(const bf16x8*)(xrb + ((q >> 1) << 9) +
                                  ((((q & 1) << 8) + (p << 4)) ^ xorb));
    f32x4 f0 = MFMA(WF[2 * 64 + lane], bxr, BS[64 + lane]);
    f32x4 f1 = MFMA(WF[3 * 64 + lane], bxr, BS[128 + lane]);
    f32x4 g0 = MFMA(WF[4 * 64 + lane], bxr, BS[192 + lane]);
    f32x4 g1 = MFMA(WF[5 * 64 + lane], bxr, BS[256 + lane]);

    f32x4 z0, z1;
#pragma unroll
    for (int r = 0; r < 4; ++r) {
        z0[r] = fast_tanh(f0[r]) * fast_sigmoid(g0[r]);
        z1[r] = fast_tanh(f1[r]) * fast_sigmoid(g1[r]);
    }
    {
        int base = (((q >> 1) << 8) + (p << 4) + ((q & 1) << 3)) ^ xorb;
        *(uint2*)(zb + base) = pk4(z0);
        *(uint2*)(zb + 512 + base) = pk4(z1);
    }

    bf16x8 bz = *(const bf16x8*)(zb + (((q << 8) + (p << 4)) ^ xorb));
    f32x4 z2 = MFMA(WF[6 * 64 + lane], bz, BS[320 + lane]);
#pragma unroll
    for (int r = 0; r < 4; ++r) z2[r] = fmaxf(z2[r], 0.f);

    size_t pos = (size_t)b * TT + tbase + p;
    size_t xidx = (pos << 4) + (q << 2);
    if (MODE != 2) {
        f32x4 xo;
#pragma unroll
        for (int r = 0; r < 4; ++r) xo[r] = xrC[r] + z2[r];
        *(uint2*)((char*)xout + pos * 32 + (q << 3)) = pk4(xo);
        if (MODE == 1) {
            *(f32x4*)(skip + xidx) = z2;
        } else {
            f32x4 s = *(const f32x4*)(skip + xidx);
#pragma unroll
            for (int r = 0; r < 4; ++r) s[r] += z2[r];
            *(f32x4*)(skip + xidx) = s;
        }
    } else {
        f32x4 s = *(const f32x4*)(skip + xidx);
        size_t ob = (size_t)b * (16 * (size_t)TT) + (size_t)(q << 2) * TT + (tbase + p);
#pragma unroll
        for (int r = 0; r < 4; ++r)
            dout[ob + (size_t)r * TT] = fmaxf(s[r] + z2[r], 0.f);
    }
}

extern "C" void kernel_launch(void* const* d_in, const int* in_sizes, int n_in,
                              void* d_out, int out_size, void* d_ws, size_t ws_size,
                              hipStream_t stream) {
    const float* x        = (const float*)d_in[0];
    const float* w1_first = (const float*)d_in[1];
    const float* b1_first = (const float*)d_in[2];
    const float* w1_post  = (const float*)d_in[3];
    const float* b1_post  = (const float*)d_in[4];
    const float* wf       = (const float*)d_in[5];
    const float* bf       = (const float*)d_in[6];
    const float* wg       = (const float*)d_in[7];
    const float* bg       = (const float*)d_in[8];
    const float* w2       = (const float*)d_in[9];
    const float* b2       = (const float*)d_in[10];

    void* X0 = d_ws;                                    // 16.78 MB single-bf16 x
    float* SK = (float*)((char*)d_ws + 33554432);       // 33.55 MB fp32 skip
    short* Wfrag = (short*)((char*)d_ws + 67108864);    // 236,544 B
    float* Bset = (float*)((char*)d_ws + 67345408);     // 202,752 B
    void* XD = d_out;                                   // x ping-pong (16.78 MB)
    float* dout = (float*)d_out;

    prep_kernel<<<33, 64, 0, stream>>>(w1_first, b1_first, w1_post, b1_post,
                                       wf, bf, wg, bg, w2, b2, Wfrag, Bset);

    dim3 sblock(256), sgrid(BB * TT / 64);  // 8192 blocks per layer

    // ALL-SINGLES plan (r27 post-mortem: fused path = 21.9us/layer > singles'
    // ~18us/layer after the single-bf16 x stream made singles memory-cheap;
    // occupancy on fused pinned at ~20% across 7 configs -> fused retired).
    // 32 x-producers alternate XD/X0 starting with XD, so L31 writes X0 and
    // L32 reads X0 while writing dout (= XD buffer) without overlap.
    int n = 1;
    const void* cur_in = (const void*)x;
    auto nxt = [&](int parity) -> void* { return (parity & 1) ? XD : X0; };

    for (int L = 0; L < 33; ++L) {
        int d = 1 << (L % 11);
        const short* WfL = Wfrag + (size_t)L * 7 * 64 * 8;
        const float* BsL = Bset + (size_t)L * 6 * 64 * 4;
        if (L == 0) {
            void* out = nxt(n);
            wn_layer<1><<<sgrid, sblock, 0, stream>>>(cur_in, out, SK, dout,
                                                      WfL, BsL, w1_first, d);
            cur_in = out; n ^= 1;
        } else if (L == 32) {
            wn_layer<2><<<sgrid, sblock, 0, stream>>>(cur_in, nullptr, SK, dout,
                                                      WfL, BsL, w1_first, d);
        } else {
            void* out = nxt(n);
            wn_layer<0><<<sgrid, sblock, 0, stream>>>(cur_in, out, SK, dout,
                                                      WfL, BsL, w1_first, d);
            cur_in = out; n ^= 1;
        }
    }
}

// Round 29
// 667.018 us; speedup vs baseline: 1.2109x; 1.2109x over previous
//
#include <hip/hip_runtime.h>

#define BB 32
#define TT 16384

typedef __attribute__((ext_vector_type(8))) short bf16x8;
typedef __attribute__((ext_vector_type(4))) float f32x4;
typedef __attribute__((ext_vector_type(4))) int i32x4;

#define MFMA(A, B, C) __builtin_amdgcn_mfma_f32_16x16x32_bf16((A), (B), (C), 0, 0, 0)

__device__ __forceinline__ unsigned short bf16_rne(float f) {
    unsigned int u = __float_as_uint(f);
    return (unsigned short)((u + 0x7FFF + ((u >> 16) & 1)) >> 16);
}
__device__ __forceinline__ float bf16_to_f(unsigned short h) {
    return __uint_as_float(((unsigned int)h) << 16);
}
// 4 f32 -> 4 bf16 (RNE) in 2 instructions; memory order short[0..3] = v[0..3]
__device__ __forceinline__ uint2 pk4(f32x4 v) {
    uint2 r;
    asm("v_cvt_pk_bf16_f32 %0, %1, %2" : "=v"(r.x) : "v"(v[0]), "v"(v[1]));
    asm("v_cvt_pk_bf16_f32 %0, %1, %2" : "=v"(r.y) : "v"(v[2]), "v"(v[3]));
    return r;
}

__device__ __forceinline__ float fast_sigmoid(float x) {
    float e = __expf(-x);
    return __builtin_amdgcn_rcpf(1.0f + e);
}
__device__ __forceinline__ float fast_tanh(float x) {
    float ax = fabsf(x);
    float e = __expf(2.0f * ax);
    float r = 1.0f - 2.0f * __builtin_amdgcn_rcpf(1.0f + e);
    return copysignf(r, x);
}

// ---------------------------------------------------------------------------
// Weight prep (verified round 6): 7 fragments + 6 bias sets per layer.
//   lane l: row = l&15 (out-ch), q = l>>4, elem j=0..7.
// f0/f1: conv1 W1 hi/lo (replicated over q>>1):  src[j] = W1[row][8*(q&1)+j]
// f2..f5: gate Wf h0, Wf h1, Wg h0, Wg h1: src[j]=W[16h+row][8*(q&1)+j][q>>1]
// f6: out W2: src[j] = W2[row][8q+j]
// ---------------------------------------------------------------------------
__global__ void prep_kernel(const float* __restrict__ w1_first,
                            const float* __restrict__ b1_first,
                            const float* __restrict__ w1_post,
                            const float* __restrict__ b1_post,
                            const float* __restrict__ wf, const float* __restrict__ bfb,
                            const float* __restrict__ wg, const float* __restrict__ bgb,
                            const float* __restrict__ w2, const float* __restrict__ b2,
                            short* __restrict__ Wfrag, float* __restrict__ Bset) {
    int L = blockIdx.x;
    int l = threadIdx.x;
    int op = l & 15;
    int q = l >> 4;
    int i0 = (q & 1) << 3;
    int tap = q >> 1;

    float gbuf[6][8];
#pragma unroll
    for (int j = 0; j < 8; ++j) {
        gbuf[0][j] = (L == 0) ? 0.f
                   : w1_post[((size_t)(L - 1) * 16 + op) * 16 + i0 + j];
        gbuf[1][j] = wf[(((size_t)L * 32 + op) * 16 + i0 + j) * 2 + tap];
        gbuf[2][j] = wf[(((size_t)L * 32 + 16 + op) * 16 + i0 + j) * 2 + tap];
        gbuf[3][j] = wg[(((size_t)L * 32 + op) * 16 + i0 + j) * 2 + tap];
        gbuf[4][j] = wg[(((size_t)L * 32 + 16 + op) * 16 + i0 + j) * 2 + tap];
        gbuf[5][j] = w2[((size_t)L * 16 + op) * 32 + (q << 3) + j];
    }

    constexpr int gsel[7] = {0, 0, 1, 2, 3, 4, 5};
    constexpr int hsel[7] = {1, 0, 1, 1, 1, 1, 1};
#pragma unroll
    for (int f = 0; f < 7; ++f) {
        size_t base = (((size_t)L * 7 + f) * 64 + l) * 8;
#pragma unroll
        for (int j = 0; j < 8; ++j) {
            float v = gbuf[gsel[f]][j];
            unsigned short h = bf16_rne(v);
            Wfrag[base + j] = hsel[f] ? (short)h
                                      : (short)bf16_rne(v - bf16_to_f(h));
        }
    }

#pragma unroll
    for (int r = 0; r < 4; ++r) {
        int c = (q << 2) + r;
        float bv[6];
        bv[0] = (L == 0) ? b1_first[c] : b1_post[(size_t)(L - 1) * 16 + c];
        bv[1] = bfb[(size_t)L * 32 + c];
        bv[2] = bfb[(size_t)L * 32 + 16 + c];
        bv[3] = bgb[(size_t)L * 32 + c];
        bv[4] = bgb[(size_t)L * 32 + 16 + c];
        bv[5] = b2[(size_t)L * 16 + c];
#pragma unroll
        for (int s = 0; s < 6; ++s)
            Bset[(((size_t)L * 6 + s) * 64 + l) * 4 + r] = bv[s];
    }
}

// conv1 at one column. Global x stream is SINGLE bf16, 32B/pos:
// bytes 0-15 = ch0-7, 16-31 = ch8-15. One MFMA with A12 (= W_hi for q<2,
// W_lo for q>=2): W_hi*x + W_lo*x = W*x.  first: raw fp32 (B,1,T) input.
__device__ __forceinline__ f32x4 conv1_eval(bool first, const void* __restrict__ xin,
                                            const float* __restrict__ w1f,
                                            int b, int tp, int q,
                                            f32x4 b1v, bf16x8 A12) {
    const f32x4 zero = {0.f, 0.f, 0.f, 0.f};
    bool valid = ((unsigned)tp) < (unsigned)TT;
    f32x4 acc = valid ? b1v : zero;
    if (first) {
        const float* xf = (const float*)xin;
        float xv = valid ? xf[(size_t)b * TT + tp] : 0.f;
        const float4* w4 = (const float4*)w1f;
        float4 w = w4[q];
        acc[0] = fmaf(w.x, xv, acc[0]);
        acc[1] = fmaf(w.y, xv, acc[1]);
        acc[2] = fmaf(w.z, xv, acc[2]);
        acc[3] = fmaf(w.w, xv, acc[3]);
    } else {
        int tpc = valid ? tp : 0;
        const bf16x8 z8 = {0, 0, 0, 0, 0, 0, 0, 0};
        const bf16x8* xp = (const bf16x8*)((const char*)xin +
                            ((size_t)b * TT + tpc) * 32 + ((q & 1) << 4));
        bf16x8 bb = valid ? *xp : z8;
        acc = MFMA(A12, bb, acc);
    }
#pragma unroll
    for (int r = 0; r < 4; ++r) acc[r] = fmaxf(acc[r], 0.f);
    return acc;
}

// ===========================================================================
// SINGLE-LAYER kernel (r26/r27-verified: single-bf16 global x stream, ~18us,
// at its ~100MB memory roofline).  MODE: 0 = middle, 1 = first, 2 = last
// ===========================================================================
template <int MODE>
__global__ __launch_bounds__(256) void wn_layer(
    const void* __restrict__ xin, void* __restrict__ xout,
    float* __restrict__ skip, float* __restrict__ dout,
    const short* __restrict__ WfragL, const float* __restrict__ BsetL,
    const float* __restrict__ w1f, int d) {
    __shared__ char sm[8192];

    const int tid = threadIdx.x;
    const int wave = tid >> 6, lane = tid & 63;
    const int p = lane & 15, q = lane >> 4;

    const int blk = ((blockIdx.x & 7) << 10) + (blockIdx.x >> 3);
    const int b = blk >> 8;
    const int tbase = ((blk & 255) << 6) + (wave << 4);
    const int pl = d >> 1, pr = d - pl;

    char* xrb = sm + wave * 1024;
    char* zb = sm + 4096 + wave * 1024;
    const int xorb = (p & 8) << 2;

    const bf16x8* WF = (const bf16x8*)WfragL;
    const f32x4* BS = (const f32x4*)BsetL;

    const f32x4 b1v = BS[lane];
    bf16x8 A12 = {0, 0, 0, 0, 0, 0, 0, 0};
    if (MODE != 1) A12 = (q < 2) ? WF[lane] : WF[64 + lane];

#pragma unroll
    for (int g = 0; g < 2; ++g) {
        int ts = tbase + (g ? pr : -pl);
        f32x4 xr = conv1_eval(MODE == 1, xin, w1f, b, ts + p, q, b1v, A12);
        *(uint2*)(xrb + (g << 9) +
                  ((((q >> 1) << 8) + (p << 4) + ((q & 1) << 3)) ^ xorb)) = pk4(xr);
    }

    f32x4 xrC = {0.f, 0.f, 0.f, 0.f};
    if (MODE != 2)
        xrC = conv1_eval(MODE == 1, xin, w1f, b, tbase + p, q, b1v, A12);

    bf16x8 bxr = *(const bf16x8*)(xrb + ((q >> 1) << 9) +
                                  ((((q & 1) << 8) + (p << 4)) ^ xorb));
    f32x4 f0 = MFMA(WF[2 * 64 + lane], bxr, BS[64 + lane]);
    f32x4 f1 = MFMA(WF[3 * 64 + lane], bxr, BS[128 + lane]);
    f32x4 g0 = MFMA(WF[4 * 64 + lane], bxr, BS[192 + lane]);
    f32x4 g1 = MFMA(WF[5 * 64 + lane], bxr, BS[256 + lane]);

    f32x4 z0, z1;
#pragma unroll
    for (int r = 0; r < 4; ++r) {
        z0[r] = fast_tanh(f0[r]) * fast_sigmoid(g0[r]);
        z1[r] = fast_tanh(f1[r]) * fast_sigmoid(g1[r]);
    }
    {
        int base = (((q >> 1) << 8) + (p << 4) + ((q & 1) << 3)) ^ xorb;
        *(uint2*)(zb + base) = pk4(z0);
        *(uint2*)(zb + 512 + base) = pk4(z1);
    }

    bf16x8 bz = *(const bf16x8*)(zb + (((q << 8) + (p << 4)) ^ xorb));
    f32x4 z2 = MFMA(WF[6 * 64 + lane], bz, BS[320 + lane]);
#pragma unroll
    for (int r = 0; r < 4; ++r) z2[r] = fmaxf(z2[r], 0.f);

    size_t pos = (size_t)b * TT + tbase + p;
    size_t xidx = (pos << 4) + (q << 2);
    if (MODE != 2) {
        f32x4 xo;
#pragma unroll
        for (int r = 0; r < 4; ++r) xo[r] = xrC[r] + z2[r];
        *(uint2*)((char*)xout + pos * 32 + (q << 3)) = pk4(xo);
        if (MODE == 1) {
            *(f32x4*)(skip + xidx) = z2;
        } else {
            f32x4 s = *(const f32x4*)(skip + xidx);
#pragma unroll
            for (int r = 0; r < 4; ++r) s[r] += z2[r];
            *(f32x4*)(skip + xidx) = s;
        }
    } else {
        f32x4 s = *(const f32x4*)(skip + xidx);
        size_t ob = (size_t)b * (16 * (size_t)TT) + (size_t)(q << 2) * TT + (tbase + p);
#pragma unroll
        for (int r = 0; r < 4; ++r)
            dout[ob + (size_t)r * TT] = fmaxf(s[r] + z2[r], 0.f);
    }
}

// ===========================================================================
// FUSED kernel (r27-verified best, 669us total): r26 structure + U
// double-buffer -> 1 barrier/layer. 256 thr / 4 waves, region 768, tiles
// T = 4m+wave, outputs [8,40) = m 2..9. Abuf is wave-private (same wave
// writes b(k) and reads a(k+1)); only U is cross-wave -> U[2] buffers with
// schedule: a(0); loop k { BAR; b(k) reads U[k&1]; a(k+1) writes U[~k&1]; }.
// LDS 77824B = A(2x12288) | U0(2x12288) | U1(2x12288) | z(4x1024).
// conv1 = ONE MFMA via A12; x stream single bf16 (r24/r26-verified).
// r28 CONTROL: all-singles = 807us (launch gap ~7-8us/dispatch) -> the
// 3-dispatch fused path is cheaper per layer; this hybrid is the optimum.
// ===========================================================================
__global__ __launch_bounds__(256, 2) void wn_fused(
    const char* __restrict__ Xin, char* __restrict__ Xout,
    float* __restrict__ skip,
    const short* __restrict__ Wfrag, const float* __restrict__ Bset,
    int Lbase, int d0p, int NL) {
    extern __shared__ char sm[];
    char* Abuf = sm;            // 2 planes x 12288 (single-bf16 x)

    const int tid = threadIdx.x;
    const int wave = tid >> 6, lane = tid & 63;
    const int p = lane & 15, q = lane >> 4;
    char* zb = sm + 73728 + wave * 1024;
    const int xorb = (p & 8) << 2;

    // bijective XCD swizzle over 1024 blocks
    const int gblk = ((blockIdx.x & 7) << 7) | (blockIdx.x >> 3);
    const int b = gblk >> 5;
    const int gt0 = ((gblk & 31) << 9) - 128;  // outputs = local pos [128,640)

    // phase 0: load x region (single bf16, 32B/pos)
#pragma unroll
    for (int jj = 0; jj < 3; ++jj) {
        int pos = jj * 256 + tid;
        int g = gt0 + pos;
        bool valid = ((unsigned)g) < (unsigned)TT;
        const char* src = Xin + ((size_t)b * TT + (valid ? g : 0)) * 32;
#pragma unroll
        for (int sub = 0; sub < 2; ++sub) {
            i32x4 v = {0, 0, 0, 0};
            if (valid) v = *(const i32x4*)(src + sub * 16);
            *(i32x4*)(Abuf + sub * 12288 + pos * 16) = v;
        }
    }
    __syncthreads();

    int uLo = 0, uHi = 48;
    f32x4 sk[8];
#pragma unroll
    for (int m = 0; m < 8; ++m) sk[m] = f32x4{0.f, 0.f, 0.f, 0.f};

    f32x4 ureg[12];

    // --- prologue: phase a for layer 0 -> U[0] + ureg
    {
        const bf16x8* WFn = (const bf16x8*)(Wfrag + (size_t)Lbase * 7 * 64 * 8);
        const f32x4* BSn = (const f32x4*)(Bset + (size_t)Lbase * 6 * 64 * 4);
        const bf16x8 A12 = (q < 2) ? WFn[lane] : WFn[64 + lane];
        const f32x4 b1v = BSn[lane];
        char* Uw = sm + 24576;  // U[0]
#pragma unroll
        for (int m = 0; m < 12; ++m) {
            int T = 4 * m + wave;
            if (T >= uLo && T < uHi) {
                int pos = T * 16 + p;
                bf16x8 bb = *(const bf16x8*)(Abuf + (q & 1) * 12288 + pos * 16);
                f32x4 acc = b1v;
                acc = MFMA(A12, bb, acc);
                bool val = ((unsigned)(gt0 + pos)) < (unsigned)TT;
#pragma unroll
                for (int r = 0; r < 4; ++r)
                    acc[r] = val ? fmaxf(acc[r], 0.f) : 0.f;
                ureg[m] = acc;
                *(uint2*)(Uw + (q >> 1) * 12288 + pos * 16 + ((q & 1) << 3)) =
                    pk4(acc);
            }
        }
    }

#pragma unroll 1
    for (int k = 0; k < NL; ++k) {
        const int L = Lbase + k;
        const int d = 1 << (d0p + k);
        const int pl = d >> 1, pr = d - pl;
        const int tl = (pl + 15) >> 4, tr = (pr + 15) >> 4;
        const bool lastk = (k == NL - 1);
        const int nLo = uLo + tl, nHi = uHi - tr;

        const bf16x8* WF = (const bf16x8*)(Wfrag + (size_t)L * 7 * 64 * 8);
        const f32x4* BS = (const f32x4*)(Bset + (size_t)L * 6 * 64 * 4);
        const bf16x8 Wf0 = WF[128 + lane], Wf1 = WF[192 + lane];
        const bf16x8 Wg0 = WF[256 + lane], Wg1 = WF[320 + lane];
        const bf16x8 W2f = WF[384 + lane];
        const f32x4 bf0 = BS[64 + lane], bf1 = BS[128 + lane];
        const f32x4 bg0 = BS[192 + lane], bg1 = BS[256 + lane];
        const f32x4 b2v = BS[320 + lane];

        char* Ur = sm + 24576 + (k & 1) * 24576;        // U[k&1]  (read)
        char* Uw = sm + 24576 + ((k + 1) & 1) * 24576;  // U[k+1&1] (write)

        __syncthreads();  // U[k&1] fully written (prologue or previous a)

        // --- phase b(k): gate + out conv + residual + skip regs
#pragma unroll
        for (int m = 0; m < 12; ++m) {
            int T = 4 * m + wave;
            bool doit = lastk ? (m >= 2 && m <= 9) : (T >= nLo && T < nHi);
            if (doit) {
                int pos = T * 16 + p;
                int tap = (q >> 1) ? pr : -pl;
                bf16x8 bxr = *(const bf16x8*)(Ur + (q & 1) * 12288 + (pos + tap) * 16);
                f32x4 f0 = MFMA(Wf0, bxr, bf0);
                f32x4 f1 = MFMA(Wf1, bxr, bf1);
                f32x4 g0 = MFMA(Wg0, bxr, bg0);
                f32x4 g1 = MFMA(Wg1, bxr, bg1);

                f32x4 z0, z1;
#pragma unroll
                for (int r = 0; r < 4; ++r) {
                    z0[r] = fast_tanh(f0[r]) * fast_sigmoid(g0[r]);
                    z1[r] = fast_tanh(f1[r]) * fast_sigmoid(g1[r]);
                }
                int zbase = (((q >> 1) << 8) + (p << 4) + ((q & 1) << 3)) ^ xorb;
                *(uint2*)(zb + zbase) = pk4(z0);
                *(uint2*)(zb + 512 + zbase) = pk4(z1);
                bf16x8 bz = *(const bf16x8*)(zb + (((q << 8) + (p << 4)) ^ xorb));
                f32x4 z2 = MFMA(W2f, bz, b2v);
#pragma unroll
                for (int r = 0; r < 4; ++r) z2[r] = fmaxf(z2[r], 0.f);

                int g = gt0 + pos;
                f32x4 xo = ureg[m] + z2;

                if (!lastk) {
                    *(uint2*)(Abuf + (q >> 1) * 12288 + pos * 16 + ((q & 1) << 3)) =
                        pk4(xo);
                } else {
                    char* gx = Xout + ((size_t)b * TT + g) * 32;
                    *(uint2*)(gx + (q << 3)) = pk4(xo);
                }
                if (m >= 2 && m <= 9) sk[m - 2] += z2;
            }
        }

        // --- phase a(k+1): conv1 of next layer from freshly-written Abuf
        // (same-wave tile ownership -> no barrier needed before this)
        if (!lastk) {
            const bf16x8* WFn = (const bf16x8*)(Wfrag + (size_t)(L + 1) * 7 * 64 * 8);
            const f32x4* BSn = (const f32x4*)(Bset + (size_t)(L + 1) * 6 * 64 * 4);
            const bf16x8 A12n = (q < 2) ? WFn[lane] : WFn[64 + lane];
            const f32x4 b1vn = BSn[lane];
#pragma unroll
            for (int m = 0; m < 12; ++m) {
                int T = 4 * m + wave;
                if (T >= nLo && T < nHi) {
                    int pos = T * 16 + p;
                    bf16x8 bb = *(const bf16x8*)(Abuf + (q & 1) * 12288 + pos * 16);
                    f32x4 acc = b1vn;
                    acc = MFMA(A12n, bb, acc);
                    bool val = ((unsigned)(gt0 + pos)) < (unsigned)TT;
#pragma unroll
                    for (int r = 0; r < 4; ++r)
                        acc[r] = val ? fmaxf(acc[r], 0.f) : 0.f;
                    ureg[m] = acc;
                    *(uint2*)(Uw + (q >> 1) * 12288 + pos * 16 + ((q & 1) << 3)) =
                        pk4(acc);
                }
            }
        }
        uLo = nLo;
        uHi = nHi;
    }

    // skip RMW: one fp32 read+write per position for all NL layers
#pragma unroll
    for (int m = 2; m <= 9; ++m) {
        int T = 4 * m + wave;
        int g = gt0 + T * 16 + p;
        float* sp = skip + (((size_t)b * TT + g) << 4) + (q << 2);
        f32x4 s = *(const f32x4*)sp;
#pragma unroll
        for (int r = 0; r < 4; ++r) s[r] += sk[m - 2][r];
        *(f32x4*)sp = s;
    }
}

extern "C" void kernel_launch(void* const* d_in, const int* in_sizes, int n_in,
                              void* d_out, int out_size, void* d_ws, size_t ws_size,
                              hipStream_t stream) {
    const float* x        = (const float*)d_in[0];
    const float* w1_first = (const float*)d_in[1];
    const float* b1_first = (const float*)d_in[2];
    const float* w1_post  = (const float*)d_in[3];
    const float* b1_post  = (const float*)d_in[4];
    const float* wf       = (const float*)d_in[5];
    const float* bf       = (const float*)d_in[6];
    const float* wg       = (const float*)d_in[7];
    const float* bg       = (const float*)d_in[8];
    const float* w2       = (const float*)d_in[9];
    const float* b2       = (const float*)d_in[10];

    void* X0 = d_ws;                                    // 16.78 MB single-bf16 x
    float* SK = (float*)((char*)d_ws + 33554432);       // 33.55 MB fp32 skip
    short* Wfrag = (short*)((char*)d_ws + 67108864);    // 236,544 B
    float* Bset = (float*)((char*)d_ws + 67345408);     // 202,752 B
    void* XD = d_out;                                   // x ping-pong (16.78 MB)
    float* dout = (float*)d_out;

    static bool attr_done = false;
    if (!attr_done) {
        hipFuncSetAttribute(reinterpret_cast<const void*>(wn_fused),
                            hipFuncAttributeMaxDynamicSharedMemorySize, 77824);
        attr_done = true;
    }

    prep_kernel<<<33, 64, 0, stream>>>(w1_first, b1_first, w1_post, b1_post,
                                       wf, bf, wg, bg, w2, b2, Wfrag, Bset);

    dim3 sblock(256), sgrid(BB * TT / 64);     // singles: 8192 blocks
    dim3 fblock(256);
    dim3 fgrid(BB * TT / 512);                 // fused: 1024 blocks

    // launch plan (r27-verified best): 15 producers; L32 reads X0 -> XD.
    int n = 0;
    const void* cur_in = (const void*)x;
    auto nxt = [&](int parity) -> void* { return (parity & 1) ? XD : X0; };

    // L0 single, MODE 1
    {
        void* out = nxt(n);
        wn_layer<1><<<sgrid, sblock, 0, stream>>>(cur_in, out, SK, dout,
                                                  Wfrag, Bset, w1_first, 1);
        cur_in = out; n ^= 1;
    }
    for (int cyc = 0; cyc < 3; ++cyc) {
        int Lb = (cyc == 0) ? 1 : 11 * cyc;
        int d0p = (cyc == 0) ? 1 : 0;
        int NL = (cyc == 0) ? 6 : 7;
        // fused small-d run
        {
            void* out = nxt(n);
            wn_fused<<<fgrid, fblock, 77824, stream>>>(
                (const char*)cur_in, (char*)out, SK, Wfrag, Bset, Lb, d0p, NL);
            cur_in = out; n ^= 1;
        }
        // large-d singles
        int Ls = Lb + NL;           // 7, 18, 29
        for (int L = Ls; L <= Ls + 3; ++L) {
            int d = 1 << (L % 11);
            const short* WfL = Wfrag + (size_t)L * 7 * 64 * 8;
            const float* BsL = Bset + (size_t)L * 6 * 64 * 4;
            if (L == 32) {
                wn_layer<2><<<sgrid, sblock, 0, stream>>>(cur_in, nullptr, SK, dout,
                                                          WfL, BsL, w1_first, d);
            } else {
                void* out = nxt(n);
                wn_layer<0><<<sgrid, sblock, 0, stream>>>(cur_in, out, SK, dout,
                                                          WfL, BsL, w1_first, d);
                cur_in = out; n ^= 1;
            }
        }
    }
}